// Round 1
// 3188.718 us; speedup vs baseline: 1.5983x; 1.5983x over previous
//
#include <hip/hip_runtime.h>

// Problem constants
#define HH 56
#define WW 56
#define WF 29     // W/2 + 1
#define CC 768
#define BB 32
#define NB 4
#define BS 192    // block size C / NUM_BLOCKS

static constexpr float INV56  = 1.0f / 56.0f;   // ortho norm per 2D transform direction
static constexpr float TWO_PI = 6.28318530717958647692f;
static constexpr float LAMBD  = 0.01f;

typedef _Float16 f16;
typedef __attribute__((ext_vector_type(8))) _Float16 f16x8;
typedef __attribute__((ext_vector_type(8))) unsigned short u16x8;
typedef __attribute__((ext_vector_type(4))) float f32x4;

__device__ __forceinline__ f16x8 neg8(f16x8 a) {
  u16x8 u = __builtin_bit_cast(u16x8, a);
  u ^= (unsigned short)0x8000;
  return __builtin_bit_cast(f16x8, u);
}

// ---------------------------------------------------------------------------
// K0: convert + transpose weights to fp16.  w[ri][g][d][n] fp32 -> Wt[ri][g][n][d] f16
// so a B-fragment (8 contiguous d per lane) is a single 16B load.
// grid 1152, block 256 (2*NB*192*192 = 294912 elements; does both layers).
// ---------------------------------------------------------------------------
__global__ __launch_bounds__(256) void k_wcvt(const float* __restrict__ w1,
                                              const float* __restrict__ w2,
                                              f16* __restrict__ W1t,
                                              f16* __restrict__ W2t) {
  const int idx = blockIdx.x * 256 + threadIdx.x;   // coalesced read index
  const int n   = idx % BS;
  const int d   = (idx / BS) % BS;
  const int rg  = idx / (BS * BS);                  // ri*NB + g
  const size_t dst = ((size_t)rg * BS + n) * BS + d;
  W1t[dst] = (f16)w1[idx];
  W2t[dst] = (f16)w2[idx];
}

// ---------------------------------------------------------------------------
// K1: rfft along W. x (B,H,W,C) fp32 -> Y[b][kw][h][c] f16 (r,i separate).
// grid (BB*HH, 3 c-chunks of 256), block 256.
// ---------------------------------------------------------------------------
__global__ __launch_bounds__(256) void k_rfft_w(const float* __restrict__ x,
                                                f16* __restrict__ Yr,
                                                f16* __restrict__ Yi) {
  __shared__ float xs[WW][256];     // 57344 B
  __shared__ float2 cst[56];
  const int t = threadIdx.x;
  if (t < 56) {
    float ang = TWO_PI * (float)t * INV56;
    cst[t] = make_float2(cosf(ang), sinf(ang));
  }
  const int bh = blockIdx.x;
  const int b = bh / HH, h = bh % HH;
  const int c0 = blockIdx.y << 8;
  const float* xp = x + ((size_t)(b * (HH * WW) + h * WW)) * CC + c0 + t;
  for (int w = 0; w < WW; ++w) xs[w][t] = xp[(size_t)w * CC];
  __syncthreads();

  const size_t obase = ((size_t)b * (WF * HH) + h) * CC + c0 + t;
  for (int kw = 0; kw < WF; ++kw) {
    float ar = 0.f, ai = 0.f;
    int ti = 0;
    for (int w = 0; w < WW; ++w) {
      float v = xs[w][t];
      float2 tw = cst[ti];
      ar = fmaf(v, tw.x, ar);
      ai = fmaf(-v, tw.y, ai);            // e^{-i theta}
      ti += kw; if (ti >= 56) ti -= 56;
    }
    size_t o = obase + (size_t)kw * (HH * CC);
    Yr[o] = (f16)(ar * INV56);
    Yi[o] = (f16)(ai * INV56);
  }
}

// ---------------------------------------------------------------------------
// K2/K4: 56-point complex DFT along H, in-place on Y (f16 storage).
// SIGN=-1 forward (e^{-i}), SIGN=+1 inverse (e^{+i}, no 1/N here).
// grid (BB*WF, 4 chunks of 192), block 256.
// ---------------------------------------------------------------------------
template <int SIGN>
__global__ __launch_bounds__(256) void k_fft_h(f16* __restrict__ Yr,
                                               f16* __restrict__ Yi) {
  __shared__ unsigned int sri[HH][BS];   // packed (r | i<<16) f16 pairs, 43008 B
  __shared__ float2 cst[56];
  const int t = threadIdx.x;
  if (t < 56) {
    float ang = TWO_PI * (float)t * INV56;
    cst[t] = make_float2(cosf(ang), sinf(ang));
  }
  const size_t base = (size_t)blockIdx.x * (HH * CC) + blockIdx.y * BS;
  for (int j = 0; j < 42; ++j) {
    int idx = t + 256 * j;               // 56*192 = 10752 = 42*256
    int h = idx / BS, c = idx % BS;
    size_t o = base + (size_t)h * CC + c;
    sri[h][c] = (unsigned int)__builtin_bit_cast(unsigned short, Yr[o]) |
                ((unsigned int)__builtin_bit_cast(unsigned short, Yi[o]) << 16);
  }
  __syncthreads();
  constexpr float S = (float)SIGN;
  for (int j = 0; j < 42; ++j) {
    int idx = t + 256 * j;
    int kh = idx / BS, c = idx % BS;
    float ar = 0.f, ai = 0.f;
    int ti = 0;
    for (int h = 0; h < HH; ++h) {
      unsigned int v = sri[h][c];
      float yr = (float)__builtin_bit_cast(f16, (unsigned short)(v & 0xffffu));
      float yi = (float)__builtin_bit_cast(f16, (unsigned short)(v >> 16));
      float2 w = cst[ti];
      float wr = w.x, wi = S * w.y;      // folds at compile time
      ar = fmaf(yr, wr, ar); ar = fmaf(-yi, wi, ar);
      ai = fmaf(yr, wi, ai); ai = fmaf(yi, wr, ai);
      ti += kh; if (ti >= 56) ti -= 56;
    }
    size_t o = base + (size_t)kh * CC + c;
    Yr[o] = (f16)ar;
    Yi[o] = (f16)ai;
  }
}

// ---------------------------------------------------------------------------
// K3: block-diagonal complex MLP on MFMA (v_mfma_f32_16x16x32_f16).
// Spectrum Y is a row-major [51968 x 768] f16 matrix (rows = (b,kw,h)).
// Per block: 64 rows x one 192-col group g. 4 waves in 2x2:
//   wave = 32 rows (2 row-tiles) x 96 cols (6 col-tiles); acc = 2*6*2*4 = 96 VGPR.
// A-frags: lane l holds row (l&15), k = 8*(l>>4)+e (8 contiguous) -> direct 16B
// global loads (layer 1) / LDS reads of H (layer 2).
// B-frags: lane l holds col (l&15), k = 8*(l>>4)+e -> 16B loads from pre-transposed
// Wt[n][k] fp16 (L2-resident, 2.4 MB total). No LDS staging of W, no K-loop barriers.
// H (relu output) routes through LDS ([64][200] f16 padded: layer-2 A reads spread
// banks at stride 400B). LDS = 51200 B -> 3 blocks/CU.
// grid (51968/64 = 812, NB), block 256.
// ---------------------------------------------------------------------------
__global__ __launch_bounds__(256, 3) void k_mix(
    f16* __restrict__ Yr, f16* __restrict__ Yi,
    const f16* __restrict__ W1t, const float* __restrict__ b1,
    const f16* __restrict__ W2t, const float* __restrict__ b2) {
  __shared__ f16 Hr[64][200], Hi[64][200];   // 25600 B each

  const int t    = threadIdx.x;
  const int wid  = t >> 6;
  const int lane = t & 63;
  const int lr   = lane & 15;   // fragment row (A) / col (B, C/D)
  const int lk   = lane >> 4;   // k-group; C/D row-group
  const int rt2  = wid >> 1;    // wave row-half: rows rt2*32 .. +31
  const int cg   = wid & 1;     // wave col-half: cols cg*96 .. +95
  const int g    = blockIdx.y;
  const int row0 = blockIdx.x * 64;

  const f16* w1r = W1t + (size_t)(g) * (BS * BS);
  const f16* w1i = W1t + (size_t)(NB + g) * (BS * BS);
  const f16* w2r = W2t + (size_t)(g) * (BS * BS);
  const f16* w2i = W2t + (size_t)(NB + g) * (BS * BS);
  const float* b1r = b1 + (size_t)g * BS;
  const float* b1i = b1 + (size_t)(NB + g) * BS;
  const float* b2r = b2 + (size_t)g * BS;
  const float* b2i = b2 + (size_t)(NB + g) * BS;

  const f32x4 Z4 = {0.f, 0.f, 0.f, 0.f};
  f32x4 accR[2][6], accI[2][6];

  // ---------------- layer 1: A from global spectrum ----------------
#pragma unroll
  for (int r = 0; r < 2; ++r)
#pragma unroll
    for (int c = 0; c < 6; ++c) { accR[r][c] = Z4; accI[r][c] = Z4; }

#pragma unroll
  for (int kt = 0; kt < 6; ++kt) {
    const int d0 = kt * 32 + lk * 8;
    f16x8 ar[2], ai[2], nai[2];
#pragma unroll
    for (int r = 0; r < 2; ++r) {
      const size_t row = (size_t)(row0 + rt2 * 32 + r * 16 + lr);
      const size_t off = row * CC + g * BS + d0;
      ar[r]  = *(const f16x8*)(Yr + off);
      ai[r]  = *(const f16x8*)(Yi + off);
      nai[r] = neg8(ai[r]);
    }
#pragma unroll
    for (int c = 0; c < 6; ++c) {
      const int n = cg * 96 + c * 16 + lr;
      const size_t boff = (size_t)n * BS + d0;
      f16x8 br = *(const f16x8*)(w1r + boff);
      f16x8 bi = *(const f16x8*)(w1i + boff);
#pragma unroll
      for (int r = 0; r < 2; ++r) {
        // Hr = Xr*Wr - Xi*Wi ; Hi = Xr*Wi + Xi*Wr
        accR[r][c] = __builtin_amdgcn_mfma_f32_16x16x32_f16(ar[r],  br, accR[r][c], 0, 0, 0);
        accR[r][c] = __builtin_amdgcn_mfma_f32_16x16x32_f16(nai[r], bi, accR[r][c], 0, 0, 0);
        accI[r][c] = __builtin_amdgcn_mfma_f32_16x16x32_f16(ar[r],  bi, accI[r][c], 0, 0, 0);
        accI[r][c] = __builtin_amdgcn_mfma_f32_16x16x32_f16(ai[r],  br, accI[r][c], 0, 0, 0);
      }
    }
  }

  // bias + relu -> H (f16, LDS).  C/D layout: col = lane&15, row = (lane>>4)*4 + j.
#pragma unroll
  for (int r = 0; r < 2; ++r) {
    const int rbase = rt2 * 32 + r * 16 + lk * 4;
#pragma unroll
    for (int c = 0; c < 6; ++c) {
      const int col = cg * 96 + c * 16 + lr;
      const float bR = b1r[col], bI = b1i[col];
#pragma unroll
      for (int j = 0; j < 4; ++j) {
        Hr[rbase + j][col] = (f16)fmaxf(accR[r][c][j] + bR, 0.f);
        Hi[rbase + j][col] = (f16)fmaxf(accI[r][c][j] + bI, 0.f);
      }
    }
  }
  __syncthreads();

  // ---------------- layer 2: A from LDS H ----------------
#pragma unroll
  for (int r = 0; r < 2; ++r)
#pragma unroll
    for (int c = 0; c < 6; ++c) { accR[r][c] = Z4; accI[r][c] = Z4; }

#pragma unroll
  for (int kt = 0; kt < 6; ++kt) {
    const int d0 = kt * 32 + lk * 8;
    f16x8 ar[2], ai[2], nai[2];
#pragma unroll
    for (int r = 0; r < 2; ++r) {
      const int rowl = rt2 * 32 + r * 16 + lr;
      ar[r]  = *(const f16x8*)(&Hr[rowl][d0]);
      ai[r]  = *(const f16x8*)(&Hi[rowl][d0]);
      nai[r] = neg8(ai[r]);
    }
#pragma unroll
    for (int c = 0; c < 6; ++c) {
      const int n = cg * 96 + c * 16 + lr;
      const size_t boff = (size_t)n * BS + d0;
      f16x8 br = *(const f16x8*)(w2r + boff);
      f16x8 bi = *(const f16x8*)(w2i + boff);
#pragma unroll
      for (int r = 0; r < 2; ++r) {
        accR[r][c] = __builtin_amdgcn_mfma_f32_16x16x32_f16(ar[r],  br, accR[r][c], 0, 0, 0);
        accR[r][c] = __builtin_amdgcn_mfma_f32_16x16x32_f16(nai[r], bi, accR[r][c], 0, 0, 0);
        accI[r][c] = __builtin_amdgcn_mfma_f32_16x16x32_f16(ar[r],  bi, accI[r][c], 0, 0, 0);
        accI[r][c] = __builtin_amdgcn_mfma_f32_16x16x32_f16(ai[r],  br, accI[r][c], 0, 0, 0);
      }
    }
  }

  // bias + softshrink -> global spectrum (in place; block owns its rows x g-cols)
#pragma unroll
  for (int r = 0; r < 2; ++r) {
    const int rbase = row0 + rt2 * 32 + r * 16 + lk * 4;
#pragma unroll
    for (int c = 0; c < 6; ++c) {
      const int col = cg * 96 + c * 16 + lr;
      const float bR = b2r[col], bI = b2i[col];
#pragma unroll
      for (int j = 0; j < 4; ++j) {
        float vr = accR[r][c][j] + bR;
        float vi = accI[r][c][j] + bI;
        float mr = fabsf(vr) - LAMBD;
        float mi = fabsf(vi) - LAMBD;
        vr = (mr > 0.f) ? copysignf(mr, vr) : 0.f;   // softshrink
        vi = (mi > 0.f) ? copysignf(mi, vi) : 0.f;
        size_t o = (size_t)(rbase + j) * CC + g * BS + col;
        Yr[o] = (f16)vr;
        Yi[o] = (f16)vi;
      }
    }
  }
}

// ---------------------------------------------------------------------------
// K5: hermitian inverse rfft along W (c2r). out fp32.
// grid (BB*HH, 3), block 256.
// ---------------------------------------------------------------------------
__global__ __launch_bounds__(256) void k_irfft_w(const f16* __restrict__ Yr,
                                                 const f16* __restrict__ Yi,
                                                 float* __restrict__ out) {
  __shared__ float sr[WF][256], si[WF][256];   // 59392 B
  __shared__ float2 cst[56];
  const int t = threadIdx.x;
  if (t < 56) {
    float ang = TWO_PI * (float)t * INV56;
    cst[t] = make_float2(cosf(ang), sinf(ang));
  }
  const int bh = blockIdx.x;
  const int b = bh / HH, h = bh % HH;
  const int c0 = blockIdx.y << 8;
  const size_t ibase = ((size_t)b * (WF * HH) + h) * CC + c0 + t;
  for (int kw = 0; kw < WF; ++kw) {
    size_t o = ibase + (size_t)kw * (HH * CC);
    float sc = (kw >= 1 && kw <= 27) ? 2.f : 1.f;
    sr[kw][t] = sc * (float)Yr[o];
    si[kw][t] = sc * (float)Yi[o];
  }
  __syncthreads();
  const float y0 = sr[0][t], yN = sr[28][t];
  float* op = out + ((size_t)(b * (HH * WW) + h * WW)) * CC + c0 + t;
  for (int w = 0; w < WW; ++w) {
    float acc = y0 + ((w & 1) ? -yN : yN);   // bin 28: cos = (-1)^w, sin = 0
    int ti = 0;
    for (int k = 1; k <= 27; ++k) {
      ti += w; if (ti >= 56) ti -= 56;       // ti = (k*w) mod 56
      float2 tw = cst[ti];
      acc = fmaf(sr[k][t], tw.x, acc);       // e^{+i theta}, real part
      acc = fmaf(-si[k][t], tw.y, acc);
    }
    op[(size_t)w * CC] = acc * INV56;
  }
}

// ---------------------------------------------------------------------------
extern "C" void kernel_launch(void* const* d_in, const int* in_sizes, int n_in,
                              void* d_out, int out_size, void* d_ws, size_t ws_size,
                              hipStream_t stream) {
  const float* x  = (const float*)d_in[0];
  const float* w1 = (const float*)d_in[1];
  const float* b1 = (const float*)d_in[2];
  const float* w2 = (const float*)d_in[3];
  const float* b2 = (const float*)d_in[4];
  float* out = (float*)d_out;

  // spectrum scratch: 2 * 32*29*56*768 f16 = 159,645,696 bytes (same as before)
  const size_t specN = (size_t)BB * WF * HH * CC;
  f16* Yr = (f16*)d_ws;
  f16* Yi = Yr + specN;

  // fp16 transposed weights live in the tail of d_out (308,281,344 B total);
  // region [301,989,888 .. 303,169,536) is scratch until k_irfft_w overwrites it.
  f16* W1t = (f16*)((char*)d_out + 301989888);
  f16* W2t = W1t + (size_t)2 * NB * BS * BS;   // 294,912 elements each

  dim3 blk(256);
  k_wcvt    <<<dim3(1152), blk, 0, stream>>>(w1, w2, W1t, W2t);
  k_rfft_w  <<<dim3(BB * HH, 3), blk, 0, stream>>>(x, Yr, Yi);
  k_fft_h<-1><<<dim3(BB * WF, 4), blk, 0, stream>>>(Yr, Yi);
  k_mix     <<<dim3(812, NB), blk, 0, stream>>>(Yr, Yi, W1t, b1, W2t, b2);
  k_fft_h<+1><<<dim3(BB * WF, 4), blk, 0, stream>>>(Yr, Yi);
  k_irfft_w <<<dim3(BB * HH, 3), blk, 0, stream>>>(Yr, Yi, out);
}

// Round 2
// 2184.051 us; speedup vs baseline: 2.3336x; 1.4600x over previous
//
#include <hip/hip_runtime.h>

// Problem constants
#define HH 56
#define WW 56
#define WF 29     // W/2 + 1
#define CC 768
#define BB 32
#define NB 4
#define BS 192    // block size C / NUM_BLOCKS

static constexpr float INV56  = 1.0f / 56.0f;   // ortho norm per 2D transform direction
static constexpr float TWO_PI = 6.28318530717958647692f;
static constexpr float LAMBD  = 0.01f;

typedef _Float16 f16;
typedef __attribute__((ext_vector_type(4))) _Float16 f16x4;
typedef __attribute__((ext_vector_type(8))) _Float16 f16x8;
typedef __attribute__((ext_vector_type(8))) unsigned short u16x8;
typedef __attribute__((ext_vector_type(4))) float f32x4;

__device__ __forceinline__ f16x8 neg8(f16x8 a) {
  u16x8 u = __builtin_bit_cast(u16x8, a);
  u ^= (unsigned short)0x8000;
  return __builtin_bit_cast(f16x8, u);
}

// ---------------------------------------------------------------------------
// K0: convert + transpose weights to fp16.  w[ri][g][d][n] fp32 -> Wt[ri][g][n][d] f16
// grid 1152, block 256.
// ---------------------------------------------------------------------------
__global__ __launch_bounds__(256) void k_wcvt(const float* __restrict__ w1,
                                              const float* __restrict__ w2,
                                              f16* __restrict__ W1t,
                                              f16* __restrict__ W2t) {
  const int idx = blockIdx.x * 256 + threadIdx.x;   // coalesced read index
  const int n   = idx % BS;
  const int d   = (idx / BS) % BS;
  const int rg  = idx / (BS * BS);                  // ri*NB + g
  const size_t dst = ((size_t)rg * BS + n) * BS + d;
  W1t[dst] = (f16)w1[idx];
  W2t[dst] = (f16)w2[idx];
}

// ---------------------------------------------------------------------------
// K1: rfft along W via MFMA.  Per block: one (b,h), 256 c-columns.
// GEMM: Out[n][c] = sum_w T[n][w] * X[w][c],  n in [0,64): 0..28 = cos->Yr,
// 32..60 = -sin->Yi (INV56 folded), rest dead.  M=c (256), N=64, K=64 (w, pad 0).
// A = X^T staged in LDS f16 [c][64], 128B rows, XOR-swizzled (byte ^= (c&7)<<4).
// B = twiddles computed in registers from cst[56] (LDS).  4 waves x (4 mt x 4 nt).
// grid (BB*HH, 3), block 256.  LDS = 33216 B.
// ---------------------------------------------------------------------------
__global__ __launch_bounds__(256) void k_rfft_w(const float* __restrict__ x,
                                                f16* __restrict__ Yr,
                                                f16* __restrict__ Yi) {
  __shared__ f16 Xt[256 * 64];      // 32768 B, swizzled
  __shared__ float2 cst[56];
  char* xb = (char*)Xt;

  const int t = threadIdx.x;
  if (t < 56) {
    float ang = TWO_PI * (float)t * INV56;
    cst[t] = make_float2(cosf(ang), sinf(ang));
  }
  const int bh = blockIdx.x;
  const int b = bh / HH, h = bh % HH;
  const int c0 = blockIdx.y << 8;

  // ---- stage X^T (thread t owns LDS row c_local = t) ----
  {
    const float* xp = x + ((size_t)(b * (HH * WW) + h * WW)) * CC + c0 + t;
    f16 v[64];
#pragma unroll
    for (int w = 0; w < 56; ++w) v[w] = (f16)xp[(size_t)w * CC];
#pragma unroll
    for (int w = 56; w < 64; ++w) v[w] = (f16)0.f;
#pragma unroll
    for (int g = 0; g < 8; ++g) {
      int byte = t * 128 + ((g * 16) ^ ((t & 7) << 4));
      *reinterpret_cast<f16x8*>(xb + byte) = *reinterpret_cast<const f16x8*>(&v[g * 8]);
    }
  }
  __syncthreads();

  const int lane = t & 63;
  const int wid  = t >> 6;
  const int lr   = lane & 15;
  const int lk   = lane >> 4;

  // ---- B fragments (twiddles) in registers ----
  f16x8 Bf[4][2];
#pragma unroll
  for (int nt = 0; nt < 4; ++nt) {
    const int n = nt * 16 + lr;
    const bool isR = (n <= 28);
    const bool isI = (n >= 32 && n <= 60);
    const int kw = isR ? n : (isI ? n - 32 : 0);
#pragma unroll
    for (int kt = 0; kt < 2; ++kt) {
      f16x8 bv;
#pragma unroll
      for (int e = 0; e < 8; ++e) {
        int w = kt * 32 + lk * 8 + e;
        float2 tw = cst[(kw * w) % 56];
        float val = isR ? (INV56 * tw.x) : (isI ? (-INV56 * tw.y) : 0.f);
        bv[e] = (f16)val;
      }
      Bf[nt][kt] = bv;
    }
  }

  // ---- MFMA ----
  const f32x4 Z4 = {0.f, 0.f, 0.f, 0.f};
  f32x4 acc[4][4];
#pragma unroll
  for (int mt = 0; mt < 4; ++mt)
#pragma unroll
    for (int nt = 0; nt < 4; ++nt) acc[mt][nt] = Z4;

#pragma unroll
  for (int kt = 0; kt < 2; ++kt) {
    f16x8 Af[4];
#pragma unroll
    for (int mt = 0; mt < 4; ++mt) {
      int row = wid * 64 + mt * 16 + lr;
      int byte = row * 128 + (((kt * 64) + lk * 16) ^ ((row & 7) << 4));
      Af[mt] = *reinterpret_cast<const f16x8*>(xb + byte);
    }
#pragma unroll
    for (int nt = 0; nt < 4; ++nt)
#pragma unroll
      for (int mt = 0; mt < 4; ++mt)
        acc[mt][nt] = __builtin_amdgcn_mfma_f32_16x16x32_f16(Af[mt], Bf[nt][kt], acc[mt][nt], 0, 0, 0);
  }

  // ---- store: lane holds col n fixed, 4 consecutive c (rows) per acc frag ----
#pragma unroll
  for (int nt = 0; nt < 4; ++nt) {
    const int n = nt * 16 + lr;
    const bool isR = (n <= 28);
    const bool isI = (n >= 32 && n <= 60);
    if (!isR && !isI) continue;
    const int kw = isR ? n : n - 32;
    f16* dst = (isR ? Yr : Yi) + ((size_t)(b * WF + kw) * HH + h) * CC + c0 + wid * 64 + lk * 4;
#pragma unroll
    for (int mt = 0; mt < 4; ++mt) {
      f16x4 v4 = { (f16)acc[mt][nt][0], (f16)acc[mt][nt][1],
                   (f16)acc[mt][nt][2], (f16)acc[mt][nt][3] };
      *reinterpret_cast<f16x4*>(dst + mt * 16) = v4;
    }
  }
}

// ---------------------------------------------------------------------------
// K2/K4: 56-point complex DFT along H, in-place on Y (f16 storage).
// grid (BB*WF, 4 chunks of 192), block 256.
// ---------------------------------------------------------------------------
template <int SIGN>
__global__ __launch_bounds__(256) void k_fft_h(f16* __restrict__ Yr,
                                               f16* __restrict__ Yi) {
  __shared__ unsigned int sri[HH][BS];   // packed (r | i<<16) f16 pairs, 43008 B
  __shared__ float2 cst[56];
  const int t = threadIdx.x;
  if (t < 56) {
    float ang = TWO_PI * (float)t * INV56;
    cst[t] = make_float2(cosf(ang), sinf(ang));
  }
  const size_t base = (size_t)blockIdx.x * (HH * CC) + blockIdx.y * BS;
  for (int j = 0; j < 42; ++j) {
    int idx = t + 256 * j;               // 56*192 = 10752 = 42*256
    int h = idx / BS, c = idx % BS;
    size_t o = base + (size_t)h * CC + c;
    sri[h][c] = (unsigned int)__builtin_bit_cast(unsigned short, Yr[o]) |
                ((unsigned int)__builtin_bit_cast(unsigned short, Yi[o]) << 16);
  }
  __syncthreads();
  constexpr float S = (float)SIGN;
  for (int j = 0; j < 42; ++j) {
    int idx = t + 256 * j;
    int kh = idx / BS, c = idx % BS;
    float ar = 0.f, ai = 0.f;
    int ti = 0;
    for (int h = 0; h < HH; ++h) {
      unsigned int v = sri[h][c];
      float yr = (float)__builtin_bit_cast(f16, (unsigned short)(v & 0xffffu));
      float yi = (float)__builtin_bit_cast(f16, (unsigned short)(v >> 16));
      float2 w = cst[ti];
      float wr = w.x, wi = S * w.y;      // folds at compile time
      ar = fmaf(yr, wr, ar); ar = fmaf(-yi, wi, ar);
      ai = fmaf(yr, wi, ai); ai = fmaf(yi, wr, ai);
      ti += kh; if (ti >= 56) ti -= 56;
    }
    size_t o = base + (size_t)kh * CC + c;
    Yr[o] = (f16)ar;
    Yi[o] = (f16)ai;
  }
}

// ---------------------------------------------------------------------------
// K3: block-diagonal complex MLP on MFMA (unchanged from round 1).
// grid (812, NB), block 256.
// ---------------------------------------------------------------------------
__global__ __launch_bounds__(256, 3) void k_mix(
    f16* __restrict__ Yr, f16* __restrict__ Yi,
    const f16* __restrict__ W1t, const float* __restrict__ b1,
    const f16* __restrict__ W2t, const float* __restrict__ b2) {
  __shared__ f16 Hr[64][200], Hi[64][200];   // 25600 B each

  const int t    = threadIdx.x;
  const int wid  = t >> 6;
  const int lane = t & 63;
  const int lr   = lane & 15;
  const int lk   = lane >> 4;
  const int rt2  = wid >> 1;
  const int cg   = wid & 1;
  const int g    = blockIdx.y;
  const int row0 = blockIdx.x * 64;

  const f16* w1r = W1t + (size_t)(g) * (BS * BS);
  const f16* w1i = W1t + (size_t)(NB + g) * (BS * BS);
  const f16* w2r = W2t + (size_t)(g) * (BS * BS);
  const f16* w2i = W2t + (size_t)(NB + g) * (BS * BS);
  const float* b1r = b1 + (size_t)g * BS;
  const float* b1i = b1 + (size_t)(NB + g) * BS;
  const float* b2r = b2 + (size_t)g * BS;
  const float* b2i = b2 + (size_t)(NB + g) * BS;

  const f32x4 Z4 = {0.f, 0.f, 0.f, 0.f};
  f32x4 accR[2][6], accI[2][6];

#pragma unroll
  for (int r = 0; r < 2; ++r)
#pragma unroll
    for (int c = 0; c < 6; ++c) { accR[r][c] = Z4; accI[r][c] = Z4; }

#pragma unroll
  for (int kt = 0; kt < 6; ++kt) {
    const int d0 = kt * 32 + lk * 8;
    f16x8 ar[2], ai[2], nai[2];
#pragma unroll
    for (int r = 0; r < 2; ++r) {
      const size_t row = (size_t)(row0 + rt2 * 32 + r * 16 + lr);
      const size_t off = row * CC + g * BS + d0;
      ar[r]  = *(const f16x8*)(Yr + off);
      ai[r]  = *(const f16x8*)(Yi + off);
      nai[r] = neg8(ai[r]);
    }
#pragma unroll
    for (int c = 0; c < 6; ++c) {
      const int n = cg * 96 + c * 16 + lr;
      const size_t boff = (size_t)n * BS + d0;
      f16x8 br = *(const f16x8*)(w1r + boff);
      f16x8 bi = *(const f16x8*)(w1i + boff);
#pragma unroll
      for (int r = 0; r < 2; ++r) {
        accR[r][c] = __builtin_amdgcn_mfma_f32_16x16x32_f16(ar[r],  br, accR[r][c], 0, 0, 0);
        accR[r][c] = __builtin_amdgcn_mfma_f32_16x16x32_f16(nai[r], bi, accR[r][c], 0, 0, 0);
        accI[r][c] = __builtin_amdgcn_mfma_f32_16x16x32_f16(ar[r],  bi, accI[r][c], 0, 0, 0);
        accI[r][c] = __builtin_amdgcn_mfma_f32_16x16x32_f16(ai[r],  br, accI[r][c], 0, 0, 0);
      }
    }
  }

#pragma unroll
  for (int r = 0; r < 2; ++r) {
    const int rbase = rt2 * 32 + r * 16 + lk * 4;
#pragma unroll
    for (int c = 0; c < 6; ++c) {
      const int col = cg * 96 + c * 16 + lr;
      const float bR = b1r[col], bI = b1i[col];
#pragma unroll
      for (int j = 0; j < 4; ++j) {
        Hr[rbase + j][col] = (f16)fmaxf(accR[r][c][j] + bR, 0.f);
        Hi[rbase + j][col] = (f16)fmaxf(accI[r][c][j] + bI, 0.f);
      }
    }
  }
  __syncthreads();

#pragma unroll
  for (int r = 0; r < 2; ++r)
#pragma unroll
    for (int c = 0; c < 6; ++c) { accR[r][c] = Z4; accI[r][c] = Z4; }

#pragma unroll
  for (int kt = 0; kt < 6; ++kt) {
    const int d0 = kt * 32 + lk * 8;
    f16x8 ar[2], ai[2], nai[2];
#pragma unroll
    for (int r = 0; r < 2; ++r) {
      const int rowl = rt2 * 32 + r * 16 + lr;
      ar[r]  = *(const f16x8*)(&Hr[rowl][d0]);
      ai[r]  = *(const f16x8*)(&Hi[rowl][d0]);
      nai[r] = neg8(ai[r]);
    }
#pragma unroll
    for (int c = 0; c < 6; ++c) {
      const int n = cg * 96 + c * 16 + lr;
      const size_t boff = (size_t)n * BS + d0;
      f16x8 br = *(const f16x8*)(w2r + boff);
      f16x8 bi = *(const f16x8*)(w2i + boff);
#pragma unroll
      for (int r = 0; r < 2; ++r) {
        accR[r][c] = __builtin_amdgcn_mfma_f32_16x16x32_f16(ar[r],  br, accR[r][c], 0, 0, 0);
        accR[r][c] = __builtin_amdgcn_mfma_f32_16x16x32_f16(nai[r], bi, accR[r][c], 0, 0, 0);
        accI[r][c] = __builtin_amdgcn_mfma_f32_16x16x32_f16(ar[r],  bi, accI[r][c], 0, 0, 0);
        accI[r][c] = __builtin_amdgcn_mfma_f32_16x16x32_f16(ai[r],  br, accI[r][c], 0, 0, 0);
      }
    }
  }

#pragma unroll
  for (int r = 0; r < 2; ++r) {
    const int rbase = row0 + rt2 * 32 + r * 16 + lk * 4;
#pragma unroll
    for (int c = 0; c < 6; ++c) {
      const int col = cg * 96 + c * 16 + lr;
      const float bR = b2r[col], bI = b2i[col];
#pragma unroll
      for (int j = 0; j < 4; ++j) {
        float vr = accR[r][c][j] + bR;
        float vi = accI[r][c][j] + bI;
        float mr = fabsf(vr) - LAMBD;
        float mi = fabsf(vi) - LAMBD;
        vr = (mr > 0.f) ? copysignf(mr, vr) : 0.f;   // softshrink
        vi = (mi > 0.f) ? copysignf(mi, vi) : 0.f;
        size_t o = (size_t)(rbase + j) * CC + g * BS + col;
        Yr[o] = (f16)vr;
        Yi[o] = (f16)vi;
      }
    }
  }
}

// ---------------------------------------------------------------------------
// K5: hermitian inverse rfft along W via MFMA.  Per block: one (b,h), 256 c.
// GEMM: out[c][w] = sum_k St[c][k] * B[k][w];  K channels: 0..28 = Yr,
// 32..60 = Yi (pad 0).  B[k][w] = sc*INV56*{cos | -sin}.  N=64 (w<56 stored).
// grid (BB*HH, 3), block 256.  LDS = 33216 B.
// ---------------------------------------------------------------------------
__global__ __launch_bounds__(256) void k_irfft_w(const f16* __restrict__ Yr,
                                                 const f16* __restrict__ Yi,
                                                 float* __restrict__ out) {
  __shared__ f16 St[256 * 64];      // 32768 B, swizzled like Xt
  __shared__ float2 cst[56];
  char* sb = (char*)St;

  const int t = threadIdx.x;
  if (t < 56) {
    float ang = TWO_PI * (float)t * INV56;
    cst[t] = make_float2(cosf(ang), sinf(ang));
  }
  const int bh = blockIdx.x;
  const int b = bh / HH, h = bh % HH;
  const int c0 = blockIdx.y << 8;

  // ---- stage spectrum^T: thread (half,p) owns rows c=2p,2p+1 for one of r/i ----
  {
    const int half = t >> 7;          // 0: Yr -> k 0..28 ; 1: Yi -> k 32..60
    const int p = t & 127;
    const f16* src = half ? Yi : Yr;
    f16 va[32], vb[32];
#pragma unroll
    for (int kw = 0; kw < 29; ++kw) {
      size_t o = ((size_t)(b * WF + kw) * HH + h) * CC + c0 + 2 * p;
      unsigned int u = *reinterpret_cast<const unsigned int*>(src + o);
      va[kw] = __builtin_bit_cast(f16, (unsigned short)(u & 0xffffu));
      vb[kw] = __builtin_bit_cast(f16, (unsigned short)(u >> 16));
    }
#pragma unroll
    for (int kw = 29; kw < 32; ++kw) { va[kw] = (f16)0.f; vb[kw] = (f16)0.f; }
    const int ca = 2 * p, cb = 2 * p + 1;
#pragma unroll
    for (int g = 0; g < 4; ++g) {
      int g2 = half * 4 + g;
      int ba = ca * 128 + ((g2 * 16) ^ ((ca & 7) << 4));
      int bb = cb * 128 + ((g2 * 16) ^ ((cb & 7) << 4));
      *reinterpret_cast<f16x8*>(sb + ba) = *reinterpret_cast<const f16x8*>(&va[g * 8]);
      *reinterpret_cast<f16x8*>(sb + bb) = *reinterpret_cast<const f16x8*>(&vb[g * 8]);
    }
  }
  __syncthreads();

  const int lane = t & 63;
  const int wid  = t >> 6;
  const int lr   = lane & 15;
  const int lk   = lane >> 4;

  // ---- B fragments (inverse twiddles, sc + INV56 folded) ----
  f16x8 Bf[4][2];
#pragma unroll
  for (int nt = 0; nt < 4; ++nt) {
    const int w = nt * 16 + lr;       // output position (w >= 56 discarded)
#pragma unroll
    for (int kt = 0; kt < 2; ++kt) {
      f16x8 bv;
#pragma unroll
      for (int e = 0; e < 8; ++e) {
        int k = kt * 32 + lk * 8 + e;
        const bool isR = (k <= 28);
        const bool isI = (k >= 32 && k <= 60);
        int kw = isR ? k : (isI ? k - 32 : 0);
        float sc = (kw >= 1 && kw <= 27) ? 2.f : 1.f;
        float2 tw = cst[(kw * w) % 56];
        float val = isR ? (sc * INV56 * tw.x) : (isI ? (-sc * INV56 * tw.y) : 0.f);
        bv[e] = (f16)val;
      }
      Bf[nt][kt] = bv;
    }
  }

  // ---- MFMA ----
  const f32x4 Z4 = {0.f, 0.f, 0.f, 0.f};
  f32x4 acc[4][4];
#pragma unroll
  for (int mt = 0; mt < 4; ++mt)
#pragma unroll
    for (int nt = 0; nt < 4; ++nt) acc[mt][nt] = Z4;

#pragma unroll
  for (int kt = 0; kt < 2; ++kt) {
    f16x8 Af[4];
#pragma unroll
    for (int mt = 0; mt < 4; ++mt) {
      int row = wid * 64 + mt * 16 + lr;
      int byte = row * 128 + (((kt * 64) + lk * 16) ^ ((row & 7) << 4));
      Af[mt] = *reinterpret_cast<const f16x8*>(sb + byte);
    }
#pragma unroll
    for (int nt = 0; nt < 4; ++nt)
#pragma unroll
      for (int mt = 0; mt < 4; ++mt)
        acc[mt][nt] = __builtin_amdgcn_mfma_f32_16x16x32_f16(Af[mt], Bf[nt][kt], acc[mt][nt], 0, 0, 0);
  }

  // ---- store fp32: lane holds col w fixed, 4 consecutive c per frag ----
#pragma unroll
  for (int nt = 0; nt < 4; ++nt) {
    const int w = nt * 16 + lr;
    if (w >= 56) continue;
    float* dst = out + ((size_t)(b * (HH * WW) + h * WW + w)) * CC + c0 + wid * 64 + lk * 4;
#pragma unroll
    for (int mt = 0; mt < 4; ++mt) {
      float4 v4 = make_float4(acc[mt][nt][0], acc[mt][nt][1],
                              acc[mt][nt][2], acc[mt][nt][3]);
      *reinterpret_cast<float4*>(dst + mt * 16) = v4;
    }
  }
}

// ---------------------------------------------------------------------------
extern "C" void kernel_launch(void* const* d_in, const int* in_sizes, int n_in,
                              void* d_out, int out_size, void* d_ws, size_t ws_size,
                              hipStream_t stream) {
  const float* x  = (const float*)d_in[0];
  const float* w1 = (const float*)d_in[1];
  const float* b1 = (const float*)d_in[2];
  const float* w2 = (const float*)d_in[3];
  const float* b2 = (const float*)d_in[4];
  float* out = (float*)d_out;

  // spectrum scratch: 2 * 32*29*56*768 f16 = 159,645,696 bytes
  const size_t specN = (size_t)BB * WF * HH * CC;
  f16* Yr = (f16*)d_ws;
  f16* Yi = Yr + specN;

  // fp16 transposed weights in the tail of d_out (consumed by k_mix, which
  // completes before k_irfft_w overwrites the region).
  f16* W1t = (f16*)((char*)d_out + 301989888);
  f16* W2t = W1t + (size_t)2 * NB * BS * BS;   // 294,912 elements each

  dim3 blk(256);
  k_wcvt    <<<dim3(1152), blk, 0, stream>>>(w1, w2, W1t, W2t);
  k_rfft_w  <<<dim3(BB * HH, 3), blk, 0, stream>>>(x, Yr, Yi);
  k_fft_h<-1><<<dim3(BB * WF, 4), blk, 0, stream>>>(Yr, Yi);
  k_mix     <<<dim3(812, NB), blk, 0, stream>>>(Yr, Yi, W1t, b1, W2t, b2);
  k_fft_h<+1><<<dim3(BB * WF, 4), blk, 0, stream>>>(Yr, Yi);
  k_irfft_w <<<dim3(BB * HH, 3), blk, 0, stream>>>(Yr, Yi, out);
}

// Round 3
// 1163.767 us; speedup vs baseline: 4.3794x; 1.8767x over previous
//
#include <hip/hip_runtime.h>

// Problem constants
#define HH 56
#define WW 56
#define WF 29     // W/2 + 1
#define CC 768
#define BB 32
#define NB 4
#define BS 192    // block size C / NUM_BLOCKS

static constexpr float INV56  = 1.0f / 56.0f;   // ortho norm per 2D transform direction
static constexpr float TWO_PI = 6.28318530717958647692f;
static constexpr float LAMBD  = 0.01f;

typedef _Float16 f16;
typedef __attribute__((ext_vector_type(4))) _Float16 f16x4;
typedef __attribute__((ext_vector_type(8))) _Float16 f16x8;
typedef __attribute__((ext_vector_type(8))) unsigned short u16x8;
typedef __attribute__((ext_vector_type(4))) float f32x4;

__device__ __forceinline__ f16x8 neg8(f16x8 a) {
  u16x8 u = __builtin_bit_cast(u16x8, a);
  u ^= (unsigned short)0x8000;
  return __builtin_bit_cast(f16x8, u);
}

// ---------------------------------------------------------------------------
// K0: convert + transpose weights to fp16.  w[ri][g][d][n] fp32 -> Wt[ri][g][n][d] f16
// grid 1152, block 256.
// ---------------------------------------------------------------------------
__global__ __launch_bounds__(256) void k_wcvt(const float* __restrict__ w1,
                                              const float* __restrict__ w2,
                                              f16* __restrict__ W1t,
                                              f16* __restrict__ W2t) {
  const int idx = blockIdx.x * 256 + threadIdx.x;   // coalesced read index
  const int n   = idx % BS;
  const int d   = (idx / BS) % BS;
  const int rg  = idx / (BS * BS);                  // ri*NB + g
  const size_t dst = ((size_t)rg * BS + n) * BS + d;
  W1t[dst] = (f16)w1[idx];
  W2t[dst] = (f16)w2[idx];
}

// ---------------------------------------------------------------------------
// K0b: H-DFT twiddle table Bt[s][ri][n=64][k=64] f16 (32 KB).
// s=0 fwd (Bi=-sin), s=1 inv (Bi=+sin).  Zero pad for n>=56 or k>=56.
// grid 64, block 256.
// ---------------------------------------------------------------------------
__global__ __launch_bounds__(256) void k_twid(f16* __restrict__ Bt) {
  const int idx = blockIdx.x * 256 + threadIdx.x;   // 16384 total
  const int k  = idx & 63;
  const int n  = (idx >> 6) & 63;
  const int ri = (idx >> 12) & 1;
  const int s  = idx >> 13;
  float val = 0.f;
  if (n < 56 && k < 56) {
    float ang = TWO_PI * (float)((n * k) % 56) * INV56;
    val = ri ? ((s ? 1.f : -1.f) * sinf(ang)) : cosf(ang);
  }
  Bt[idx] = (f16)val;
}

// ---------------------------------------------------------------------------
// K1: rfft along W via MFMA (unchanged from round 2).
// grid (BB*HH, 3), block 256.
// ---------------------------------------------------------------------------
__global__ __launch_bounds__(256) void k_rfft_w(const float* __restrict__ x,
                                                f16* __restrict__ Yr,
                                                f16* __restrict__ Yi) {
  __shared__ f16 Xt[256 * 64];      // 32768 B, swizzled
  __shared__ float2 cst[56];
  char* xb = (char*)Xt;

  const int t = threadIdx.x;
  if (t < 56) {
    float ang = TWO_PI * (float)t * INV56;
    cst[t] = make_float2(cosf(ang), sinf(ang));
  }
  const int bh = blockIdx.x;
  const int b = bh / HH, h = bh % HH;
  const int c0 = blockIdx.y << 8;

  // ---- stage X^T (thread t owns LDS row c_local = t) ----
  {
    const float* xp = x + ((size_t)(b * (HH * WW) + h * WW)) * CC + c0 + t;
    f16 v[64];
#pragma unroll
    for (int w = 0; w < 56; ++w) v[w] = (f16)xp[(size_t)w * CC];
#pragma unroll
    for (int w = 56; w < 64; ++w) v[w] = (f16)0.f;
#pragma unroll
    for (int g = 0; g < 8; ++g) {
      int byte = t * 128 + ((g * 16) ^ ((t & 7) << 4));
      *reinterpret_cast<f16x8*>(xb + byte) = *reinterpret_cast<const f16x8*>(&v[g * 8]);
    }
  }
  __syncthreads();

  const int lane = t & 63;
  const int wid  = t >> 6;
  const int lr   = lane & 15;
  const int lk   = lane >> 4;

  // ---- B fragments (twiddles) in registers ----
  f16x8 Bf[4][2];
#pragma unroll
  for (int nt = 0; nt < 4; ++nt) {
    const int n = nt * 16 + lr;
    const bool isR = (n <= 28);
    const bool isI = (n >= 32 && n <= 60);
    const int kw = isR ? n : (isI ? n - 32 : 0);
#pragma unroll
    for (int kt = 0; kt < 2; ++kt) {
      f16x8 bv;
#pragma unroll
      for (int e = 0; e < 8; ++e) {
        int w = kt * 32 + lk * 8 + e;
        float2 tw = cst[(kw * w) % 56];
        float val = isR ? (INV56 * tw.x) : (isI ? (-INV56 * tw.y) : 0.f);
        bv[e] = (f16)val;
      }
      Bf[nt][kt] = bv;
    }
  }

  // ---- MFMA ----
  const f32x4 Z4 = {0.f, 0.f, 0.f, 0.f};
  f32x4 acc[4][4];
#pragma unroll
  for (int mt = 0; mt < 4; ++mt)
#pragma unroll
    for (int nt = 0; nt < 4; ++nt) acc[mt][nt] = Z4;

#pragma unroll
  for (int kt = 0; kt < 2; ++kt) {
    f16x8 Af[4];
#pragma unroll
    for (int mt = 0; mt < 4; ++mt) {
      int row = wid * 64 + mt * 16 + lr;
      int byte = row * 128 + (((kt * 64) + lk * 16) ^ ((row & 7) << 4));
      Af[mt] = *reinterpret_cast<const f16x8*>(xb + byte);
    }
#pragma unroll
    for (int nt = 0; nt < 4; ++nt)
#pragma unroll
      for (int mt = 0; mt < 4; ++mt)
        acc[mt][nt] = __builtin_amdgcn_mfma_f32_16x16x32_f16(Af[mt], Bf[nt][kt], acc[mt][nt], 0, 0, 0);
  }

  // ---- store ----
#pragma unroll
  for (int nt = 0; nt < 4; ++nt) {
    const int n = nt * 16 + lr;
    const bool isR = (n <= 28);
    const bool isI = (n >= 32 && n <= 60);
    if (!isR && !isI) continue;
    const int kw = isR ? n : n - 32;
    f16* dst = (isR ? Yr : Yi) + ((size_t)(b * WF + kw) * HH + h) * CC + c0 + wid * 64 + lk * 4;
#pragma unroll
    for (int mt = 0; mt < 4; ++mt) {
      f16x4 v4 = { (f16)acc[mt][nt][0], (f16)acc[mt][nt][1],
                   (f16)acc[mt][nt][2], (f16)acc[mt][nt][3] };
      *reinterpret_cast<f16x4*>(dst + mt * 16) = v4;
    }
  }
}

// ---------------------------------------------------------------------------
// K2/K4: 56-point complex DFT along H via MFMA, in-place on Y.
// Per block: one (b,kw) = blockIdx.x, 256-c chunk = blockIdx.y.
// GEMM: Out[kh][c] = sum_h T[kh][h] Y[h][c];  M=c(256), N=64(kh pad), K=64(h pad).
// A = Yr^T, Yi^T staged in LDS [256][64] f16, XOR-swizzled.  B from global
// twiddle table Bt (L2-resident).  Complex = 4 MFMA chains, 128 MFMA/wave.
// grid (BB*WF, 3), block 256.  LDS = 65536 B -> 2 blocks/CU.
// ---------------------------------------------------------------------------
template <int SIGN>
__global__ __launch_bounds__(256) void k_fft_h(f16* __restrict__ Yr,
                                               f16* __restrict__ Yi,
                                               const f16* __restrict__ Bt) {
  __shared__ f16 A2[2][256 * 64];   // 32768 B each: [0]=Yr^T, [1]=Yi^T

  const int t = threadIdx.x;
  const size_t base = (size_t)blockIdx.x * (HH * CC);
  const int c0 = blockIdx.y << 8;

  // ---- stage both spectra transposed (thread t owns LDS row c_local = t) ----
#pragma unroll
  for (int arr = 0; arr < 2; ++arr) {
    const f16* src = (arr ? Yi : Yr) + base + c0 + t;
    char* ab = (char*)A2[arr];
    f16 v[64];
#pragma unroll
    for (int h = 0; h < 56; ++h) v[h] = src[(size_t)h * CC];
#pragma unroll
    for (int h = 56; h < 64; ++h) v[h] = (f16)0.f;
#pragma unroll
    for (int g = 0; g < 8; ++g) {
      int byte = t * 128 + ((g * 16) ^ ((t & 7) << 4));
      *reinterpret_cast<f16x8*>(ab + byte) = *reinterpret_cast<const f16x8*>(&v[g * 8]);
    }
  }
  __syncthreads();

  const int lane = t & 63;
  const int wid  = t >> 6;
  const int lr   = lane & 15;
  const int lk   = lane >> 4;

  // ---- B fragments from the precomputed table ----
  const f16* B = Bt + (SIGN > 0 ? 8192 : 0);
  f16x8 Brf[4][2], Bif[4][2];
#pragma unroll
  for (int nt = 0; nt < 4; ++nt) {
    const int n = nt * 16 + lr;
#pragma unroll
    for (int kt = 0; kt < 2; ++kt) {
      Brf[nt][kt] = *(const f16x8*)(B +        (size_t)n * 64 + kt * 32 + lk * 8);
      Bif[nt][kt] = *(const f16x8*)(B + 4096 + (size_t)n * 64 + kt * 32 + lk * 8);
    }
  }

  // ---- MFMA: accR = Ar*Br - Ai*Bi ; accI = Ar*Bi + Ai*Br ----
  const f32x4 Z4 = {0.f, 0.f, 0.f, 0.f};
  f32x4 accR[4][4], accI[4][4];
#pragma unroll
  for (int mt = 0; mt < 4; ++mt)
#pragma unroll
    for (int nt = 0; nt < 4; ++nt) { accR[mt][nt] = Z4; accI[mt][nt] = Z4; }

  char* arb = (char*)A2[0];
  char* aib = (char*)A2[1];
#pragma unroll
  for (int kt = 0; kt < 2; ++kt) {
    f16x8 ar[4], ai[4], nai[4];
#pragma unroll
    for (int mt = 0; mt < 4; ++mt) {
      int row = wid * 64 + mt * 16 + lr;
      int byte = row * 128 + (((kt * 64) + lk * 16) ^ ((row & 7) << 4));
      ar[mt]  = *reinterpret_cast<const f16x8*>(arb + byte);
      ai[mt]  = *reinterpret_cast<const f16x8*>(aib + byte);
      nai[mt] = neg8(ai[mt]);
    }
#pragma unroll
    for (int nt = 0; nt < 4; ++nt)
#pragma unroll
      for (int mt = 0; mt < 4; ++mt) {
        accR[mt][nt] = __builtin_amdgcn_mfma_f32_16x16x32_f16(ar[mt],  Brf[nt][kt], accR[mt][nt], 0, 0, 0);
        accR[mt][nt] = __builtin_amdgcn_mfma_f32_16x16x32_f16(nai[mt], Bif[nt][kt], accR[mt][nt], 0, 0, 0);
        accI[mt][nt] = __builtin_amdgcn_mfma_f32_16x16x32_f16(ar[mt],  Bif[nt][kt], accI[mt][nt], 0, 0, 0);
        accI[mt][nt] = __builtin_amdgcn_mfma_f32_16x16x32_f16(ai[mt],  Brf[nt][kt], accI[mt][nt], 0, 0, 0);
      }
  }

  // ---- store in place (block owns its (b,kw) x c-chunk exclusively) ----
#pragma unroll
  for (int nt = 0; nt < 4; ++nt) {
    const int n = nt * 16 + lr;
    if (n >= 56) continue;
    f16* dR = Yr + base + (size_t)n * CC + c0 + wid * 64 + lk * 4;
    f16* dI = Yi + base + (size_t)n * CC + c0 + wid * 64 + lk * 4;
#pragma unroll
    for (int mt = 0; mt < 4; ++mt) {
      f16x4 vr = { (f16)accR[mt][nt][0], (f16)accR[mt][nt][1],
                   (f16)accR[mt][nt][2], (f16)accR[mt][nt][3] };
      f16x4 vi = { (f16)accI[mt][nt][0], (f16)accI[mt][nt][1],
                   (f16)accI[mt][nt][2], (f16)accI[mt][nt][3] };
      *reinterpret_cast<f16x4*>(dR + mt * 16) = vr;
      *reinterpret_cast<f16x4*>(dI + mt * 16) = vi;
    }
  }
}

// ---------------------------------------------------------------------------
// K3: block-diagonal complex MLP on MFMA (unchanged).
// grid (812, NB), block 256.
// ---------------------------------------------------------------------------
__global__ __launch_bounds__(256, 3) void k_mix(
    f16* __restrict__ Yr, f16* __restrict__ Yi,
    const f16* __restrict__ W1t, const float* __restrict__ b1,
    const f16* __restrict__ W2t, const float* __restrict__ b2) {
  __shared__ f16 Hr[64][200], Hi[64][200];   // 25600 B each

  const int t    = threadIdx.x;
  const int wid  = t >> 6;
  const int lane = t & 63;
  const int lr   = lane & 15;
  const int lk   = lane >> 4;
  const int rt2  = wid >> 1;
  const int cg   = wid & 1;
  const int g    = blockIdx.y;
  const int row0 = blockIdx.x * 64;

  const f16* w1r = W1t + (size_t)(g) * (BS * BS);
  const f16* w1i = W1t + (size_t)(NB + g) * (BS * BS);
  const f16* w2r = W2t + (size_t)(g) * (BS * BS);
  const f16* w2i = W2t + (size_t)(NB + g) * (BS * BS);
  const float* b1r = b1 + (size_t)g * BS;
  const float* b1i = b1 + (size_t)(NB + g) * BS;
  const float* b2r = b2 + (size_t)g * BS;
  const float* b2i = b2 + (size_t)(NB + g) * BS;

  const f32x4 Z4 = {0.f, 0.f, 0.f, 0.f};
  f32x4 accR[2][6], accI[2][6];

#pragma unroll
  for (int r = 0; r < 2; ++r)
#pragma unroll
    for (int c = 0; c < 6; ++c) { accR[r][c] = Z4; accI[r][c] = Z4; }

#pragma unroll
  for (int kt = 0; kt < 6; ++kt) {
    const int d0 = kt * 32 + lk * 8;
    f16x8 ar[2], ai[2], nai[2];
#pragma unroll
    for (int r = 0; r < 2; ++r) {
      const size_t row = (size_t)(row0 + rt2 * 32 + r * 16 + lr);
      const size_t off = row * CC + g * BS + d0;
      ar[r]  = *(const f16x8*)(Yr + off);
      ai[r]  = *(const f16x8*)(Yi + off);
      nai[r] = neg8(ai[r]);
    }
#pragma unroll
    for (int c = 0; c < 6; ++c) {
      const int n = cg * 96 + c * 16 + lr;
      const size_t boff = (size_t)n * BS + d0;
      f16x8 br = *(const f16x8*)(w1r + boff);
      f16x8 bi = *(const f16x8*)(w1i + boff);
#pragma unroll
      for (int r = 0; r < 2; ++r) {
        accR[r][c] = __builtin_amdgcn_mfma_f32_16x16x32_f16(ar[r],  br, accR[r][c], 0, 0, 0);
        accR[r][c] = __builtin_amdgcn_mfma_f32_16x16x32_f16(nai[r], bi, accR[r][c], 0, 0, 0);
        accI[r][c] = __builtin_amdgcn_mfma_f32_16x16x32_f16(ar[r],  bi, accI[r][c], 0, 0, 0);
        accI[r][c] = __builtin_amdgcn_mfma_f32_16x16x32_f16(ai[r],  br, accI[r][c], 0, 0, 0);
      }
    }
  }

#pragma unroll
  for (int r = 0; r < 2; ++r) {
    const int rbase = rt2 * 32 + r * 16 + lk * 4;
#pragma unroll
    for (int c = 0; c < 6; ++c) {
      const int col = cg * 96 + c * 16 + lr;
      const float bR = b1r[col], bI = b1i[col];
#pragma unroll
      for (int j = 0; j < 4; ++j) {
        Hr[rbase + j][col] = (f16)fmaxf(accR[r][c][j] + bR, 0.f);
        Hi[rbase + j][col] = (f16)fmaxf(accI[r][c][j] + bI, 0.f);
      }
    }
  }
  __syncthreads();

#pragma unroll
  for (int r = 0; r < 2; ++r)
#pragma unroll
    for (int c = 0; c < 6; ++c) { accR[r][c] = Z4; accI[r][c] = Z4; }

#pragma unroll
  for (int kt = 0; kt < 6; ++kt) {
    const int d0 = kt * 32 + lk * 8;
    f16x8 ar[2], ai[2], nai[2];
#pragma unroll
    for (int r = 0; r < 2; ++r) {
      const int rowl = rt2 * 32 + r * 16 + lr;
      ar[r]  = *(const f16x8*)(&Hr[rowl][d0]);
      ai[r]  = *(const f16x8*)(&Hi[rowl][d0]);
      nai[r] = neg8(ai[r]);
    }
#pragma unroll
    for (int c = 0; c < 6; ++c) {
      const int n = cg * 96 + c * 16 + lr;
      const size_t boff = (size_t)n * BS + d0;
      f16x8 br = *(const f16x8*)(w2r + boff);
      f16x8 bi = *(const f16x8*)(w2i + boff);
#pragma unroll
      for (int r = 0; r < 2; ++r) {
        accR[r][c] = __builtin_amdgcn_mfma_f32_16x16x32_f16(ar[r],  br, accR[r][c], 0, 0, 0);
        accR[r][c] = __builtin_amdgcn_mfma_f32_16x16x32_f16(nai[r], bi, accR[r][c], 0, 0, 0);
        accI[r][c] = __builtin_amdgcn_mfma_f32_16x16x32_f16(ar[r],  bi, accI[r][c], 0, 0, 0);
        accI[r][c] = __builtin_amdgcn_mfma_f32_16x16x32_f16(ai[r],  br, accI[r][c], 0, 0, 0);
      }
    }
  }

#pragma unroll
  for (int r = 0; r < 2; ++r) {
    const int rbase = row0 + rt2 * 32 + r * 16 + lk * 4;
#pragma unroll
    for (int c = 0; c < 6; ++c) {
      const int col = cg * 96 + c * 16 + lr;
      const float bR = b2r[col], bI = b2i[col];
#pragma unroll
      for (int j = 0; j < 4; ++j) {
        float vr = accR[r][c][j] + bR;
        float vi = accI[r][c][j] + bI;
        float mr = fabsf(vr) - LAMBD;
        float mi = fabsf(vi) - LAMBD;
        vr = (mr > 0.f) ? copysignf(mr, vr) : 0.f;   // softshrink
        vi = (mi > 0.f) ? copysignf(mi, vi) : 0.f;
        size_t o = (size_t)(rbase + j) * CC + g * BS + col;
        Yr[o] = (f16)vr;
        Yi[o] = (f16)vi;
      }
    }
  }
}

// ---------------------------------------------------------------------------
// K5: hermitian inverse rfft along W via MFMA (unchanged from round 2).
// grid (BB*HH, 3), block 256.
// ---------------------------------------------------------------------------
__global__ __launch_bounds__(256) void k_irfft_w(const f16* __restrict__ Yr,
                                                 const f16* __restrict__ Yi,
                                                 float* __restrict__ out) {
  __shared__ f16 St[256 * 64];      // 32768 B, swizzled like Xt
  __shared__ float2 cst[56];
  char* sb = (char*)St;

  const int t = threadIdx.x;
  if (t < 56) {
    float ang = TWO_PI * (float)t * INV56;
    cst[t] = make_float2(cosf(ang), sinf(ang));
  }
  const int bh = blockIdx.x;
  const int b = bh / HH, h = bh % HH;
  const int c0 = blockIdx.y << 8;

  // ---- stage spectrum^T ----
  {
    const int half = t >> 7;          // 0: Yr -> k 0..28 ; 1: Yi -> k 32..60
    const int p = t & 127;
    const f16* src = half ? Yi : Yr;
    f16 va[32], vb[32];
#pragma unroll
    for (int kw = 0; kw < 29; ++kw) {
      size_t o = ((size_t)(b * WF + kw) * HH + h) * CC + c0 + 2 * p;
      unsigned int u = *reinterpret_cast<const unsigned int*>(src + o);
      va[kw] = __builtin_bit_cast(f16, (unsigned short)(u & 0xffffu));
      vb[kw] = __builtin_bit_cast(f16, (unsigned short)(u >> 16));
    }
#pragma unroll
    for (int kw = 29; kw < 32; ++kw) { va[kw] = (f16)0.f; vb[kw] = (f16)0.f; }
    const int ca = 2 * p, cb = 2 * p + 1;
#pragma unroll
    for (int g = 0; g < 4; ++g) {
      int g2 = half * 4 + g;
      int ba = ca * 128 + ((g2 * 16) ^ ((ca & 7) << 4));
      int bb = cb * 128 + ((g2 * 16) ^ ((cb & 7) << 4));
      *reinterpret_cast<f16x8*>(sb + ba) = *reinterpret_cast<const f16x8*>(&va[g * 8]);
      *reinterpret_cast<f16x8*>(sb + bb) = *reinterpret_cast<const f16x8*>(&vb[g * 8]);
    }
  }
  __syncthreads();

  const int lane = t & 63;
  const int wid  = t >> 6;
  const int lr   = lane & 15;
  const int lk   = lane >> 4;

  // ---- B fragments (inverse twiddles, sc + INV56 folded) ----
  f16x8 Bf[4][2];
#pragma unroll
  for (int nt = 0; nt < 4; ++nt) {
    const int w = nt * 16 + lr;       // output position (w >= 56 discarded)
#pragma unroll
    for (int kt = 0; kt < 2; ++kt) {
      f16x8 bv;
#pragma unroll
      for (int e = 0; e < 8; ++e) {
        int k = kt * 32 + lk * 8 + e;
        const bool isR = (k <= 28);
        const bool isI = (k >= 32 && k <= 60);
        int kw = isR ? k : (isI ? k - 32 : 0);
        float sc = (kw >= 1 && kw <= 27) ? 2.f : 1.f;
        float2 tw = cst[(kw * w) % 56];
        float val = isR ? (sc * INV56 * tw.x) : (isI ? (-sc * INV56 * tw.y) : 0.f);
        bv[e] = (f16)val;
      }
      Bf[nt][kt] = bv;
    }
  }

  // ---- MFMA ----
  const f32x4 Z4 = {0.f, 0.f, 0.f, 0.f};
  f32x4 acc[4][4];
#pragma unroll
  for (int mt = 0; mt < 4; ++mt)
#pragma unroll
    for (int nt = 0; nt < 4; ++nt) acc[mt][nt] = Z4;

#pragma unroll
  for (int kt = 0; kt < 2; ++kt) {
    f16x8 Af[4];
#pragma unroll
    for (int mt = 0; mt < 4; ++mt) {
      int row = wid * 64 + mt * 16 + lr;
      int byte = row * 128 + (((kt * 64) + lk * 16) ^ ((row & 7) << 4));
      Af[mt] = *reinterpret_cast<const f16x8*>(sb + byte);
    }
#pragma unroll
    for (int nt = 0; nt < 4; ++nt)
#pragma unroll
      for (int mt = 0; mt < 4; ++mt)
        acc[mt][nt] = __builtin_amdgcn_mfma_f32_16x16x32_f16(Af[mt], Bf[nt][kt], acc[mt][nt], 0, 0, 0);
  }

  // ---- store fp32 ----
#pragma unroll
  for (int nt = 0; nt < 4; ++nt) {
    const int w = nt * 16 + lr;
    if (w >= 56) continue;
    float* dst = out + ((size_t)(b * (HH * WW) + h * WW + w)) * CC + c0 + wid * 64 + lk * 4;
#pragma unroll
    for (int mt = 0; mt < 4; ++mt) {
      float4 v4 = make_float4(acc[mt][nt][0], acc[mt][nt][1],
                              acc[mt][nt][2], acc[mt][nt][3]);
      *reinterpret_cast<float4*>(dst + mt * 16) = v4;
    }
  }
}

// ---------------------------------------------------------------------------
extern "C" void kernel_launch(void* const* d_in, const int* in_sizes, int n_in,
                              void* d_out, int out_size, void* d_ws, size_t ws_size,
                              hipStream_t stream) {
  const float* x  = (const float*)d_in[0];
  const float* w1 = (const float*)d_in[1];
  const float* b1 = (const float*)d_in[2];
  const float* w2 = (const float*)d_in[3];
  const float* b2 = (const float*)d_in[4];
  float* out = (float*)d_out;

  // spectrum scratch: 2 * 32*29*56*768 f16 = 159,645,696 bytes
  const size_t specN = (size_t)BB * WF * HH * CC;
  f16* Yr = (f16*)d_ws;
  f16* Yi = Yr + specN;

  // fp16 weights + twiddle table in the tail of d_out (sequential stream:
  // consumed by k_fft_h / k_mix, overwritten only by the final k_irfft_w).
  f16* W1t = (f16*)((char*)d_out + 301989888);
  f16* W2t = W1t + (size_t)2 * NB * BS * BS;   // 294,912 elements each
  f16* Bt  = W2t + (size_t)2 * NB * BS * BS;   // 16,384 elements (32 KB)

  dim3 blk(256);
  k_wcvt    <<<dim3(1152), blk, 0, stream>>>(w1, w2, W1t, W2t);
  k_twid    <<<dim3(64), blk, 0, stream>>>(Bt);
  k_rfft_w  <<<dim3(BB * HH, 3), blk, 0, stream>>>(x, Yr, Yi);
  k_fft_h<-1><<<dim3(BB * WF, 3), blk, 0, stream>>>(Yr, Yi, Bt);
  k_mix     <<<dim3(812, NB), blk, 0, stream>>>(Yr, Yi, W1t, b1, W2t, b2);
  k_fft_h<+1><<<dim3(BB * WF, 3), blk, 0, stream>>>(Yr, Yi, Bt);
  k_irfft_w <<<dim3(BB * HH, 3), blk, 0, stream>>>(Yr, Yi, out);
}